// Round 17
// baseline (511.303 us; speedup 1.0000x reference)
//
#include <hip/hip_runtime.h>

#define D_   256
#define HW_  1024
#define N_   65536
#define K_   1024
#define ND_  16777216
// sound one-sided fp16 phase1 score error bound: S1*A + B
#define MARGIN_A 2.0e-6f
#define MARGIN_B 3.5e-5f

typedef __attribute__((ext_vector_type(8))) short bf16x8;
typedef __attribute__((ext_vector_type(8))) _Float16 f16x8;
typedef __attribute__((ext_vector_type(4))) float f32x4;

union f16cv { _Float16 h; unsigned short u; };

__device__ inline unsigned short f16_bits(float v) {
    f16cv c; c.h = (_Float16)v; return c.u;
}

#define GLL16(g, l) __builtin_amdgcn_global_load_lds( \
    (const __attribute__((address_space(1))) unsigned int*)(const void*)(g), \
    (__attribute__((address_space(3))) unsigned int*)(void*)(l), 16, 0, 0)

// ---- k_startup: blocks 0..1023 = init(E) + zeroing; 1024..3071 = zsplit(Z) ----
__global__ __launch_bounds__(256) void k_startup(const float* __restrict__ Z,
                                                 const float* __restrict__ E,
                                                 unsigned short* __restrict__ Eh,
                                                 float* __restrict__ Et,
                                                 float* __restrict__ e2f,
                                                 double* __restrict__ e2d,
                                                 unsigned short* __restrict__ Zh,
                                                 float* __restrict__ S1,
                                                 double* __restrict__ zpart,
                                                 int* __restrict__ counts,
                                                 int* __restrict__ nflag_f,
                                                 int* __restrict__ nflag_c,
                                                 int* __restrict__ done,
                                                 double* __restrict__ loss_acc) {
    int t = threadIdx.x;
    if (blockIdx.x < 1024) {
        // ---- init: E -> f16 (x1024) + Et (f32 transpose) + e2 (f32/f64) ----
        __shared__ double sh[256];
        int k = blockIdx.x;
        float v = E[(size_t)k * D_ + t];
        Eh[(size_t)k * D_ + t] = f16_bits(v * 1024.f);  // exact pow2 scale
        Et[(size_t)t * K_ + k] = v;
        sh[t] = (double)v * v;
        __syncthreads();
        for (int off = 128; off; off >>= 1) {
            if (t < off) sh[t] += sh[t + off];
            __syncthreads();
        }
        if (t == 0) { e2f[k] = (float)sh[0]; e2d[k] = sh[0]; }
        // zeroing (no concurrent writer of these cells inside this kernel)
        if (k < 4) counts[k * 256 + t] = 0;
        else if (k == 4 && t == 0) { *nflag_f = 0; *nflag_c = 0; *loss_acc = 0.0; }
        else if (k == 5) { done[t] = 0; done[256 + t] = 0; }
        return;
    }
    // ---- zsplit: Z -> Zh [n][d] f16 + S1 + per-block sum(z^2) -> zpart ----
    __shared__ unsigned short lh[32][264];
    __shared__ float sabs[32][32];
    __shared__ double dsh[256];
    int bid = blockIdx.x - 1024;          // 2048 = 64 b * 32 chunks
    int b = bid >> 5, hw0 = (bid & 31) * 32;
    int qd = t & 7, ds = t >> 3;          // hw quad 0..7, d-slot 0..31
    const float* zb = Z + (size_t)b * (D_ * HW_) + hw0 + 4 * qd;
    float a0 = 0.f, a1 = 0.f, a2 = 0.f, a3 = 0.f;
    double qsum = 0.0;
    #pragma unroll
    for (int j = 0; j < 8; ++j) {
        int d = ds + 32 * j;
        float4 v = *(const float4*)(zb + (size_t)d * HW_);
        lh[4 * qd + 0][d] = f16_bits(v.x);
        lh[4 * qd + 1][d] = f16_bits(v.y);
        lh[4 * qd + 2][d] = f16_bits(v.z);
        lh[4 * qd + 3][d] = f16_bits(v.w);
        a0 += fabsf(v.x); a1 += fabsf(v.y); a2 += fabsf(v.z); a3 += fabsf(v.w);
        qsum = fma((double)v.x, (double)v.x, qsum);
        qsum = fma((double)v.y, (double)v.y, qsum);
        qsum = fma((double)v.z, (double)v.z, qsum);
        qsum = fma((double)v.w, (double)v.w, qsum);
    }
    sabs[4 * qd + 0][ds] = a0;
    sabs[4 * qd + 1][ds] = a1;
    sabs[4 * qd + 2][ds] = a2;
    sabs[4 * qd + 3][ds] = a3;
    dsh[t] = qsum;
    __syncthreads();
    for (int off = 128; off; off >>= 1) {
        if (t < off) dsh[t] += dsh[t + off];
        __syncthreads();
    }
    if (t == 0) zpart[bid] = dsh[0];      // plain store; folded in k_gatherfinal

    int row = t >> 3, cb = t & 7;
    size_t nbase = ((size_t)b * HW_ + hw0 + row) * D_;
    #pragma unroll
    for (int jj = 0; jj < 4; ++jj) {
        int ch = cb + jj * 8;
        *(bf16x8*)(Zh + nbase + ch * 8) = *(const bf16x8*)&lh[row][ch * 8];
    }
    if (t < 32) {
        float s = 0.f;
        #pragma unroll
        for (int q = 0; q < 32; ++q) s += sabs[t][q];
        S1[(size_t)b * HW_ + hw0 + t] = s;
    }
}

// ---- k_phase1: 128x128 f16 MFMA GEMM (BK=128, frozen) + fused last-block merge ----
__global__ __launch_bounds__(256) void k_phase1(const unsigned short* __restrict__ Zh,
                                                const unsigned short* __restrict__ Eh,
                                                const float* __restrict__ e2f,
                                                const float* __restrict__ S1,
                                                float4* __restrict__ pmq,
                                                int* __restrict__ idx,
                                                int* __restrict__ counts,
                                                int* __restrict__ c8,
                                                unsigned char* __restrict__ ncand,
                                                int* __restrict__ list_c,
                                                int* __restrict__ nflag_c,
                                                int* __restrict__ list_f,
                                                int* __restrict__ nflag_f,
                                                int* __restrict__ done,
                                                double* __restrict__ loss_acc) {
    __shared__ __align__(16) unsigned short lds[4 * 8192];  // 64KB
    __shared__ int slast;
    int t = threadIdx.x, w = t >> 6, l = t & 63;
    int bid = blockIdx.x;
    int xcd = bid & 7, slot = bid >> 3;
    int mb = xcd * 64 + (slot >> 3);
    int nb = slot & 7;
    int wr = w >> 1, wc = w & 1;

    const unsigned short* src =
        (w < 2 ? Zh + (size_t)mb * 128 * D_ : Eh + (size_t)nb * 128 * D_)
        + (size_t)(w & 1) * 64 * D_;
    unsigned short* myl0 = &lds[__builtin_amdgcn_readfirstlane(w * 4096)];
    unsigned short* myl1 = &lds[__builtin_amdgcn_readfirstlane(16384 + w * 4096)];

    int Rl = l >> 3;
    int lc = (l & 7) ^ (l >> 3);           // pre-swizzled source chunk (rule #21)

    f32x4 acc[4][4];
    #pragma unroll
    for (int m = 0; m < 4; ++m)
        #pragma unroll
        for (int nn = 0; nn < 4; ++nn) acc[m][nn] = (f32x4){0.f, 0.f, 0.f, 0.f};

    for (int ktp = 0; ktp < 2; ++ktp) {    // 2 phases of BK=128
        #pragma unroll
        for (int i = 0; i < 8; ++i) {
            const unsigned short* g = src + (size_t)(i * 8 + Rl) * D_ + (ktp * 2) * 64 + lc * 8;
            GLL16(g, myl0 + i * 512);
        }
        #pragma unroll
        for (int i = 0; i < 8; ++i) {
            const unsigned short* g = src + (size_t)(i * 8 + Rl) * D_ + (ktp * 2 + 1) * 64 + lc * 8;
            GLL16(g, myl1 + i * 512);
        }
        __syncthreads();
        int q = l >> 4;
        #pragma unroll
        for (int kt2 = 0; kt2 < 2; ++kt2) {
            const char* Ab = (const char*)lds + kt2 * 32768;
            const char* Bb = Ab + 16384;
            #pragma unroll
            for (int ks2 = 0; ks2 < 2; ++ks2) {
                int pcb = ((ks2 * 4 + q) ^ (l & 7)) * 16;
                f16x8 ah[4];
                #pragma unroll
                for (int m = 0; m < 4; ++m)
                    ah[m] = *(const f16x8*)(Ab + (wr * 64 + m * 16 + (l & 15)) * 128 + pcb);
                #pragma unroll
                for (int nn = 0; nn < 4; ++nn) {
                    f16x8 bh = *(const f16x8*)(Bb + (wc * 64 + nn * 16 + (l & 15)) * 128 + pcb);
                    #pragma unroll
                    for (int m = 0; m < 4; ++m)
                        acc[m][nn] = __builtin_amdgcn_mfma_f32_16x16x32_f16(ah[m], bh, acc[m][nn], 0, 0, 0);
                }
            }
        }
        __syncthreads();
    }

    // ---- cheap top-2 epilogue ----
    float m1v[4][4], m2v[4][4]; int i1v[4][4];
    #pragma unroll
    for (int m = 0; m < 4; ++m)
        #pragma unroll
        for (int r = 0; r < 4; ++r) { m1v[m][r] = 3.4e38f; m2v[m][r] = 3.4e38f; i1v[m][r] = 0; }

    #pragma unroll
    for (int nn = 0; nn < 4; ++nn) {
        int c = nb * 128 + wc * 64 + nn * 16 + (l & 15);
        float e2 = e2f[c];
        #pragma unroll
        for (int m = 0; m < 4; ++m)
            #pragma unroll
            for (int r = 0; r < 4; ++r) {
                float s = fmaf(-2.f / 1024.f, acc[m][nn][r], e2);   // unscale dot
                if (s < m1v[m][r])      { m2v[m][r] = m1v[m][r]; m1v[m][r] = s; i1v[m][r] = c; }
                else if (s < m2v[m][r]) { m2v[m][r] = s; }
            }
    }
    #pragma unroll
    for (int off = 1; off < 16; off <<= 1) {
        #pragma unroll
        for (int m = 0; m < 4; ++m)
            #pragma unroll
            for (int r = 0; r < 4; ++r) {
                float o1 = __shfl_xor(m1v[m][r], off, 64);
                float o2 = __shfl_xor(m2v[m][r], off, 64);
                int   oi = __shfl_xor(i1v[m][r], off, 64);
                if (o1 < m1v[m][r]) { m2v[m][r] = fminf(m1v[m][r], o2); m1v[m][r] = o1; i1v[m][r] = oi; }
                else                { m2v[m][r] = fminf(m2v[m][r], o1); }
            }
    }
    __syncthreads();                       // reuse lds as exchange
    float* ex1 = (float*)lds;              // [4 waves][64 rows]
    float* ex2 = ex1 + 256;
    int*   exi = (int*)(ex2 + 256);
    if ((l & 15) == 0) {
        int qq = l >> 4;
        #pragma unroll
        for (int m = 0; m < 4; ++m)
            #pragma unroll
            for (int r = 0; r < 4; ++r) {
                int e = (wr * 2 + wc) * 64 + m * 16 + qq * 4 + r;
                ex1[e] = m1v[m][r]; ex2[e] = m2v[m][r]; exi[e] = i1v[m][r];
            }
    }
    __syncthreads();
    if (t < 128) {
        int wr2 = t >> 6, rw = t & 63;
        int e0 = (wr2 * 2 + 0) * 64 + rw, e1 = (wr2 * 2 + 1) * 64 + rw;
        float a1 = ex1[e0], a2 = ex2[e0]; int ai = exi[e0];
        float b1 = ex1[e1], b2 = ex2[e1]; int bi = exi[e1];
        float M1, M2; int I1;
        if (a1 <= b1) { M1 = a1; I1 = ai; M2 = fminf(a2, b1); }
        else          { M1 = b1; I1 = bi; M2 = fminf(b2, a1); }
        size_t p = (size_t)nb * N_ + (size_t)mb * 128 + t;
        pmq[p] = make_float4(M1, M2, __int_as_float(I1), 0.f);
    }

    // ---- decoupled last-sibling merge (device-scope fences: G16-safe) ----
    __threadfence();                       // release: pm writes visible agent-wide
    if (t == 0) slast = atomicAdd(&done[mb], 1);
    __syncthreads();
    if (slast != 7) return;                // block-uniform
    __threadfence();                       // acquire: invalidate stale caches

    double m1loss = 0.0;
    if (t < 128) {
        int n = mb * 128 + t;
        float a1v[8], a2v[8]; int aiv[8];
        float M1 = 3.4e38f, M2 = 3.4e38f; int I1 = 0;
        #pragma unroll
        for (int q8 = 0; q8 < 8; ++q8) {
            float4 v = pmq[(size_t)q8 * N_ + n];
            a1v[q8] = v.x; a2v[q8] = v.y; aiv[q8] = __float_as_int(v.z);
            if (v.x < M1) { M2 = fminf(M1, v.y); M1 = v.x; I1 = aiv[q8]; }
            else          { M2 = fminf(M2, v.x); }
        }
        idx[n] = I1;
        atomicAdd(&counts[I1], 1);
        float thr = M1 + fmaf(S1[n], MARGIN_A, MARGIN_B);
        bool fl = M2 < thr;
        bool needfull = false;
        int cnt = 0;
        if (fl) {
            #pragma unroll
            for (int q8 = 0; q8 < 8; ++q8) {
                if (a2v[q8] < thr) needfull = true;
                if (a1v[q8] < thr) ++cnt;
            }
        }
        bool candrow = fl && !needfull;
        bool fullrow = fl && needfull;
        if (candrow) {
            ncand[n] = (unsigned char)cnt;
            int pos = 0;
            #pragma unroll
            for (int q8 = 0; q8 < 8; ++q8)
                if (a1v[q8] < thr) c8[(size_t)n * 8 + (pos++)] = aiv[q8];  // ascending
        }
        unsigned long long mc = __ballot(candrow);
        if (mc) {
            int base = 0;
            if (l == 0) base = atomicAdd(nflag_c, __popcll(mc));
            base = __shfl(base, 0, 64);
            if (candrow) list_c[base + __popcll(mc & ((1ull << l) - 1ull))] = n;
        }
        unsigned long long mf = __ballot(fullrow);
        if (mf) {
            int base = 0;
            if (l == 0) base = atomicAdd(nflag_f, __popcll(mf));
            base = __shfl(base, 0, 64);
            if (fullrow) list_f[base + __popcll(mf & ((1ull << l) - 1ull))] = n;
        }
        m1loss = (double)M1;
    }
    double* msh = (double*)lds;
    msh[t] = m1loss;
    __syncthreads();
    for (int off = 128; off; off >>= 1) {
        if (t < off) msh[t] += msh[t + off];
        __syncthreads();
    }
    if (t == 0) atomicAdd(loss_acc, msh[0]);
}

// ---- k_fixup: blocks 0..1023 = full-K f64 rescan; 1024..1279 = cand2 rescore ----
__global__ __launch_bounds__(256) void k_fixup(const float* __restrict__ Z,
                                               const float* __restrict__ E,
                                               const float* __restrict__ Et,
                                               const double* __restrict__ e2d,
                                               const int* __restrict__ c8,
                                               const unsigned char* __restrict__ ncand,
                                               const int* __restrict__ list_c,
                                               const int* __restrict__ nflag_c,
                                               const int* __restrict__ list_f,
                                               const int* __restrict__ nflag_f,
                                               int* __restrict__ idx,
                                               int* __restrict__ counts) {
    __shared__ float  zs[8][257];
    __shared__ int    sn[8];
    __shared__ double rbv[8][4];
    __shared__ int    rbi[8][4];
    int t = threadIdx.x, w = t >> 6, l = t & 63;

    if (blockIdx.x >= 1024) {
        // ---- cand2: exact f64 rescore of <=8 known candidates, one wave per row ----
        int nf = *nflag_c;
        int gw = (blockIdx.x - 1024) * 4 + w;     // 1024 waves
        for (int ii = gw; ii < nf; ii += 1024) {
            int n = list_c[ii];
            int b = n >> 10, hw = n & (HW_ - 1);
            const float* zp = Z + (size_t)b * (D_ * HW_) + hw;
            double z0 = (double)zp[(size_t)(l      ) * HW_];
            double z1 = (double)zp[(size_t)(l +  64) * HW_];
            double z2 = (double)zp[(size_t)(l + 128) * HW_];
            double z3 = (double)zp[(size_t)(l + 192) * HW_];
            int nc = ncand[n];
            double bv = 1e300; int bi = 0;
            for (int j = 0; j < nc; ++j) {        // candidates ascend in code index
                int c = c8[(size_t)n * 8 + j];
                const float* er = E + (size_t)c * D_;
                double s = z0 * (double)er[l];
                s = fma(z1, (double)er[l +  64], s);
                s = fma(z2, (double)er[l + 128], s);
                s = fma(z3, (double)er[l + 192], s);
                #pragma unroll
                for (int off = 32; off; off >>= 1) s += __shfl_xor(s, off, 64);
                double sc = fma(-2.0, s, e2d[c]);  // z^2 cancels in ranking
                if (sc < bv || (sc == bv && c < bi)) { bv = sc; bi = c; }
            }
            if (l == 0) {
                int old = idx[n];
                if (bi != old) {
                    idx[n] = bi;
                    atomicSub(&counts[old], 1);
                    atomicAdd(&counts[bi], 1);
                }
            }
        }
        return;
    }

    // ---- rescan8: exact f64 full-K fallback, 8 rows/chunk, 8x d-unroll ----
    int nf = *nflag_f;
    double ed0 = e2d[4 * t + 0], ed1 = e2d[4 * t + 1];
    double ed2 = e2d[4 * t + 2], ed3 = e2d[4 * t + 3];

    for (int ch = blockIdx.x; ch * 8 < nf; ch += 1024) {
        __syncthreads();
        int i0 = ch * 8;
        int vc = min(8, nf - i0);
        if (t < 8) sn[t] = list_f[i0 + min(t, vc - 1)];
        __syncthreads();

        #pragma unroll
        for (int j = 0; j < 8; ++j) {
            int n = sn[j];
            zs[j][t] = Z[(size_t)(n >> 10) * (D_ * HW_) + (size_t)t * HW_ + (n & (HW_ - 1))];
        }
        __syncthreads();

        double s[8][4];
        #pragma unroll
        for (int r = 0; r < 8; ++r)
            s[r][0] = s[r][1] = s[r][2] = s[r][3] = 0.0;

        for (int d0 = 0; d0 < 256; d0 += 8) {
            float4 e4v[8];
            #pragma unroll
            for (int u = 0; u < 8; ++u)
                e4v[u] = *(const float4*)(Et + (size_t)(d0 + u) * K_ + 4 * t);
            #pragma unroll
            for (int u = 0; u < 8; ++u) {
                double ex = (double)e4v[u].x, ey = (double)e4v[u].y;
                double ez = (double)e4v[u].z, ew = (double)e4v[u].w;
                #pragma unroll
                for (int r = 0; r < 8; ++r) {
                    double zv = (double)zs[r][d0 + u];
                    s[r][0] = fma(zv, ex, s[r][0]);
                    s[r][1] = fma(zv, ey, s[r][1]);
                    s[r][2] = fma(zv, ez, s[r][2]);
                    s[r][3] = fma(zv, ew, s[r][3]);
                }
            }
        }

        #pragma unroll
        for (int r = 0; r < 8; ++r) {
            double bv = fma(-2.0, s[r][0], ed0); int bi = 4 * t;
            double c1 = fma(-2.0, s[r][1], ed1);
            double c2 = fma(-2.0, s[r][2], ed2);
            double c3 = fma(-2.0, s[r][3], ed3);
            if (c1 < bv) { bv = c1; bi = 4 * t + 1; }
            if (c2 < bv) { bv = c2; bi = 4 * t + 2; }
            if (c3 < bv) { bv = c3; bi = 4 * t + 3; }
            #pragma unroll
            for (int off = 1; off < 64; off <<= 1) {
                double ov = __shfl_xor(bv, off, 64);
                int    oi = __shfl_xor(bi, off, 64);
                if (ov < bv || (ov == bv && oi < bi)) { bv = ov; bi = oi; }
            }
            if (l == 0) { rbv[r][w] = bv; rbi[r][w] = bi; }
        }
        __syncthreads();

        if (t < vc) {
            double bv = rbv[t][0]; int bi = rbi[t][0];
            #pragma unroll
            for (int ww = 1; ww < 4; ++ww) {
                double ov = rbv[t][ww]; int oi = rbi[t][ww];
                if (ov < bv || (ov == bv && oi < bi)) { bv = ov; bi = oi; }
            }
            int n = sn[t];
            int old = idx[n];
            if (bi != old) {
                idx[n] = bi;
                atomicSub(&counts[old], 1);
                atomicAdd(&counts[bi], 1);
            }
        }
    }
}

// ---- k_gatherfinal: blocks 0..2047 = E-scatter to NCHW out; block 2048 = scalars ----
__global__ __launch_bounds__(256) void k_gatherfinal(const float* __restrict__ E,
                                                     const int* __restrict__ idx,
                                                     const int* __restrict__ counts,
                                                     const double* __restrict__ zpart,
                                                     const double* __restrict__ loss_acc,
                                                     float* __restrict__ out) {
    int t = threadIdx.x;
    if (blockIdx.x == 2048) {
        __shared__ double sh[256], sh2[256];
        double s = 0.0;
        for (int k = t; k < K_; k += 256) {
            double p = (double)counts[k] / (double)N_;
            s += p * log(p + 1e-10);
        }
        double zs = 0.0;
        #pragma unroll
        for (int j = 0; j < 8; ++j) zs += zpart[t + 256 * j];
        sh[t] = s; sh2[t] = zs;
        __syncthreads();
        for (int off = 128; off; off >>= 1) {
            if (t < off) { sh[t] += sh[t + off]; sh2[t] += sh2[t + off]; }
            __syncthreads();
        }
        if (t == 0) {
            out[0]       = (float)(((*loss_acc) + sh2[0]) / (double)ND_ * 1.25);
            out[1 + ND_] = (float)exp(-sh[0]);
        }
        return;
    }
    __shared__ float ecache[32][257];
    __shared__ int sidx[32];
    int n0 = blockIdx.x * 32;                 // 2048 blocks
    int b = n0 >> 10, hw0 = n0 & (HW_ - 1);
    if (t < 32) sidx[t] = idx[n0 + t];
    __syncthreads();
    #pragma unroll 8
    for (int j = 0; j < 32; ++j)
        ecache[j][t] = E[(size_t)sidx[j] * D_ + t];
    __syncthreads();
    int hw = t & 31, cq = t >> 5;
    float* ob = out + 1 + (size_t)b * (D_ * HW_) + hw0 + hw;
    #pragma unroll 8
    for (int jj = 0; jj < 32; ++jj) {
        int c = cq * 32 + jj;
        ob[(size_t)c * HW_] = ecache[hw][c];
    }
}

extern "C" void kernel_launch(void* const* d_in, const int* in_sizes, int n_in,
                              void* d_out, int out_size, void* d_ws, size_t ws_size,
                              hipStream_t stream) {
    (void)in_sizes; (void)n_in; (void)out_size; (void)ws_size;
    const float* Z = (const float*)d_in[0];
    const float* E = (const float*)d_in[1];
    float* out = (float*)d_out;

    char* ws = (char*)d_ws;
    unsigned short* Zh       = (unsigned short*)(ws);              // 32 MB
    unsigned short* Eh       = (unsigned short*)(ws + 33554432);   // 512 KB
    float*          Et       = (float*)(ws + 34078720);            // 1 MB
    float*          e2f      = (float*)(ws + 35127296);            // 4 KB
    double*         e2d      = (double*)(ws + 35131392);           // 8 KB
    float*          S1       = (float*)(ws + 35139584);            // 256 KB
    float4*         pmq      = (float4*)(ws + 35401728);           // 8 MB
    int*            idx      = (int*)  (ws + 43790336);            // 256 KB
    int*            list_f   = (int*)  (ws + 44052480);            // 256 KB
    int*            list_c   = (int*)  (ws + 44314624);            // 256 KB
    int*            c8       = (int*)  (ws + 44576768);            // 2 MB
    unsigned char*  ncand    = (unsigned char*)(ws + 46673920);    // 64 KB
    int*            counts   = (int*)  (ws + 46739456);            // 4 KB
    int*            nflag_f  = (int*)  (ws + 46743552);            // 64 B
    int*            nflag_c  = (int*)  (ws + 46743616);            // 64 B
    double*         loss_acc = (double*)(ws + 46743680);           // 64 B
    double*         zpart    = (double*)(ws + 46743744);           // 16 KB
    int*            done     = (int*)  (ws + 46760128);            // 2 KB

    k_startup    <<<dim3(3072), dim3(256), 0, stream>>>(Z, E, Eh, Et, e2f, e2d, Zh, S1,
                                                        zpart, counts, nflag_f, nflag_c, done, loss_acc);
    k_phase1     <<<dim3(4096), dim3(256), 0, stream>>>(Zh, Eh, e2f, S1, pmq, idx, counts,
                                                        c8, ncand, list_c, nflag_c, list_f, nflag_f,
                                                        done, loss_acc);
    k_fixup      <<<dim3(1280), dim3(256), 0, stream>>>(Z, E, Et, e2d, c8, ncand,
                                                        list_c, nflag_c, list_f, nflag_f, idx, counts);
    k_gatherfinal<<<dim3(2049), dim3(256), 0, stream>>>(E, idx, counts, zpart, loss_acc, out);
}

// Round 18
// 212.844 us; speedup vs baseline: 2.4022x; 2.4022x over previous
//
#include <hip/hip_runtime.h>

#define D_   256
#define HW_  1024
#define N_   65536
#define K_   1024
#define ND_  16777216
// sound one-sided fp16 phase1 score error bound: S1*A + B
#define MARGIN_A 2.0e-6f
#define MARGIN_B 3.5e-5f

typedef __attribute__((ext_vector_type(8))) short bf16x8;
typedef __attribute__((ext_vector_type(8))) _Float16 f16x8;
typedef __attribute__((ext_vector_type(4))) float f32x4;

union f16cv { _Float16 h; unsigned short u; };

__device__ inline unsigned short f16_bits(float v) {
    f16cv c; c.h = (_Float16)v; return c.u;
}

#define GLL16(g, l) __builtin_amdgcn_global_load_lds( \
    (const __attribute__((address_space(1))) unsigned int*)(const void*)(g), \
    (__attribute__((address_space(3))) unsigned int*)(void*)(l), 16, 0, 0)

// ---- k_startup: blocks 0..1023 = init(E) + zeroing; 1024..3071 = zsplit(Z) ----
__global__ __launch_bounds__(256) void k_startup(const float* __restrict__ Z,
                                                 const float* __restrict__ E,
                                                 unsigned short* __restrict__ Eh,
                                                 float* __restrict__ Et,
                                                 float* __restrict__ e2f,
                                                 double* __restrict__ e2d,
                                                 unsigned short* __restrict__ Zh,
                                                 float* __restrict__ S1,
                                                 double* __restrict__ zpart,
                                                 int* __restrict__ counts,
                                                 int* __restrict__ nflag_f,
                                                 int* __restrict__ nflag_c,
                                                 double* __restrict__ loss_acc) {
    int t = threadIdx.x;
    if (blockIdx.x < 1024) {
        // ---- init: E -> f16 (x1024) + Et (f32 transpose) + e2 (f32/f64) ----
        __shared__ double sh[256];
        int k = blockIdx.x;
        float v = E[(size_t)k * D_ + t];
        Eh[(size_t)k * D_ + t] = f16_bits(v * 1024.f);  // exact pow2 scale
        Et[(size_t)t * K_ + k] = v;
        sh[t] = (double)v * v;
        __syncthreads();
        for (int off = 128; off; off >>= 1) {
            if (t < off) sh[t] += sh[t + off];
            __syncthreads();
        }
        if (t == 0) { e2f[k] = (float)sh[0]; e2d[k] = sh[0]; }
        // zeroing (no concurrent writer of these cells inside this kernel)
        if (k < 4) counts[k * 256 + t] = 0;
        else if (k == 4 && t == 0) { *nflag_f = 0; *nflag_c = 0; *loss_acc = 0.0; }
        return;
    }
    // ---- zsplit: Z -> Zh [n][d] f16 + S1 + per-block sum(z^2) -> zpart ----
    __shared__ unsigned short lh[32][264];
    __shared__ float sabs[32][32];
    __shared__ double dsh[256];
    int bid = blockIdx.x - 1024;          // 2048 = 64 b * 32 chunks
    int b = bid >> 5, hw0 = (bid & 31) * 32;
    int qd = t & 7, ds = t >> 3;          // hw quad 0..7, d-slot 0..31
    const float* zb = Z + (size_t)b * (D_ * HW_) + hw0 + 4 * qd;
    float a0 = 0.f, a1 = 0.f, a2 = 0.f, a3 = 0.f;
    double qsum = 0.0;
    #pragma unroll
    for (int j = 0; j < 8; ++j) {
        int d = ds + 32 * j;
        float4 v = *(const float4*)(zb + (size_t)d * HW_);
        lh[4 * qd + 0][d] = f16_bits(v.x);
        lh[4 * qd + 1][d] = f16_bits(v.y);
        lh[4 * qd + 2][d] = f16_bits(v.z);
        lh[4 * qd + 3][d] = f16_bits(v.w);
        a0 += fabsf(v.x); a1 += fabsf(v.y); a2 += fabsf(v.z); a3 += fabsf(v.w);
        qsum = fma((double)v.x, (double)v.x, qsum);
        qsum = fma((double)v.y, (double)v.y, qsum);
        qsum = fma((double)v.z, (double)v.z, qsum);
        qsum = fma((double)v.w, (double)v.w, qsum);
    }
    sabs[4 * qd + 0][ds] = a0;
    sabs[4 * qd + 1][ds] = a1;
    sabs[4 * qd + 2][ds] = a2;
    sabs[4 * qd + 3][ds] = a3;
    dsh[t] = qsum;
    __syncthreads();
    for (int off = 128; off; off >>= 1) {
        if (t < off) dsh[t] += dsh[t + off];
        __syncthreads();
    }
    if (t == 0) zpart[bid] = dsh[0];      // plain store; folded in k_merge

    int row = t >> 3, cb = t & 7;
    size_t nbase = ((size_t)b * HW_ + hw0 + row) * D_;
    #pragma unroll
    for (int jj = 0; jj < 4; ++jj) {
        int ch = cb + jj * 8;
        *(bf16x8*)(Zh + nbase + ch * 8) = *(const bf16x8*)&lh[row][ch * 8];
    }
    if (t < 32) {
        float s = 0.f;
        #pragma unroll
        for (int q = 0; q < 32; ++q) s += sabs[t][q];
        S1[(size_t)b * HW_ + hw0 + t] = s;
    }
}

// ---- k_phase1: 128x128 f16 MFMA GEMM, BK=128 (frozen: 102 us plateau) ----
__global__ __launch_bounds__(256) void k_phase1(const unsigned short* __restrict__ Zh,
                                                const unsigned short* __restrict__ Eh,
                                                const float* __restrict__ e2f,
                                                float* __restrict__ pm1,
                                                float* __restrict__ pm2,
                                                int* __restrict__ pi1) {
    __shared__ __align__(16) unsigned short lds[4 * 8192];  // 64KB
    int t = threadIdx.x, w = t >> 6, l = t & 63;
    int bid = blockIdx.x;
    int xcd = bid & 7, slot = bid >> 3;
    int mb = xcd * 64 + (slot >> 3);
    int nb = slot & 7;
    int wr = w >> 1, wc = w & 1;

    const unsigned short* src =
        (w < 2 ? Zh + (size_t)mb * 128 * D_ : Eh + (size_t)nb * 128 * D_)
        + (size_t)(w & 1) * 64 * D_;
    unsigned short* myl0 = &lds[__builtin_amdgcn_readfirstlane(w * 4096)];
    unsigned short* myl1 = &lds[__builtin_amdgcn_readfirstlane(16384 + w * 4096)];

    int Rl = l >> 3;
    int lc = (l & 7) ^ (l >> 3);           // pre-swizzled source chunk (rule #21)

    f32x4 acc[4][4];
    #pragma unroll
    for (int m = 0; m < 4; ++m)
        #pragma unroll
        for (int nn = 0; nn < 4; ++nn) acc[m][nn] = (f32x4){0.f, 0.f, 0.f, 0.f};

    for (int ktp = 0; ktp < 2; ++ktp) {    // 2 phases of BK=128
        #pragma unroll
        for (int i = 0; i < 8; ++i) {
            const unsigned short* g = src + (size_t)(i * 8 + Rl) * D_ + (ktp * 2) * 64 + lc * 8;
            GLL16(g, myl0 + i * 512);
        }
        #pragma unroll
        for (int i = 0; i < 8; ++i) {
            const unsigned short* g = src + (size_t)(i * 8 + Rl) * D_ + (ktp * 2 + 1) * 64 + lc * 8;
            GLL16(g, myl1 + i * 512);
        }
        __syncthreads();
        int q = l >> 4;
        #pragma unroll
        for (int kt2 = 0; kt2 < 2; ++kt2) {
            const char* Ab = (const char*)lds + kt2 * 32768;
            const char* Bb = Ab + 16384;
            #pragma unroll
            for (int ks2 = 0; ks2 < 2; ++ks2) {
                int pcb = ((ks2 * 4 + q) ^ (l & 7)) * 16;
                f16x8 ah[4];
                #pragma unroll
                for (int m = 0; m < 4; ++m)
                    ah[m] = *(const f16x8*)(Ab + (wr * 64 + m * 16 + (l & 15)) * 128 + pcb);
                #pragma unroll
                for (int nn = 0; nn < 4; ++nn) {
                    f16x8 bh = *(const f16x8*)(Bb + (wc * 64 + nn * 16 + (l & 15)) * 128 + pcb);
                    #pragma unroll
                    for (int m = 0; m < 4; ++m)
                        acc[m][nn] = __builtin_amdgcn_mfma_f32_16x16x32_f16(ah[m], bh, acc[m][nn], 0, 0, 0);
                }
            }
        }
        __syncthreads();
    }

    // ---- cheap top-2 epilogue ----
    float m1v[4][4], m2v[4][4]; int i1v[4][4];
    #pragma unroll
    for (int m = 0; m < 4; ++m)
        #pragma unroll
        for (int r = 0; r < 4; ++r) { m1v[m][r] = 3.4e38f; m2v[m][r] = 3.4e38f; i1v[m][r] = 0; }

    #pragma unroll
    for (int nn = 0; nn < 4; ++nn) {
        int c = nb * 128 + wc * 64 + nn * 16 + (l & 15);
        float e2 = e2f[c];
        #pragma unroll
        for (int m = 0; m < 4; ++m)
            #pragma unroll
            for (int r = 0; r < 4; ++r) {
                float s = fmaf(-2.f / 1024.f, acc[m][nn][r], e2);   // unscale dot
                if (s < m1v[m][r])      { m2v[m][r] = m1v[m][r]; m1v[m][r] = s; i1v[m][r] = c; }
                else if (s < m2v[m][r]) { m2v[m][r] = s; }
            }
    }
    #pragma unroll
    for (int off = 1; off < 16; off <<= 1) {
        #pragma unroll
        for (int m = 0; m < 4; ++m)
            #pragma unroll
            for (int r = 0; r < 4; ++r) {
                float o1 = __shfl_xor(m1v[m][r], off, 64);
                float o2 = __shfl_xor(m2v[m][r], off, 64);
                int   oi = __shfl_xor(i1v[m][r], off, 64);
                if (o1 < m1v[m][r]) { m2v[m][r] = fminf(m1v[m][r], o2); m1v[m][r] = o1; i1v[m][r] = oi; }
                else                { m2v[m][r] = fminf(m2v[m][r], o1); }
            }
    }
    __syncthreads();                       // reuse lds as exchange
    float* ex1 = (float*)lds;              // [4 waves][64 rows]
    float* ex2 = ex1 + 256;
    int*   exi = (int*)(ex2 + 256);
    if ((l & 15) == 0) {
        int qq = l >> 4;
        #pragma unroll
        for (int m = 0; m < 4; ++m)
            #pragma unroll
            for (int r = 0; r < 4; ++r) {
                int e = (wr * 2 + wc) * 64 + m * 16 + qq * 4 + r;
                ex1[e] = m1v[m][r]; ex2[e] = m2v[m][r]; exi[e] = i1v[m][r];
            }
    }
    __syncthreads();
    if (t < 128) {
        int wr2 = t >> 6, rw = t & 63;
        int e0 = (wr2 * 2 + 0) * 64 + rw, e1 = (wr2 * 2 + 1) * 64 + rw;
        float a1 = ex1[e0], a2 = ex2[e0]; int ai = exi[e0];
        float b1 = ex1[e1], b2 = ex2[e1]; int bi = exi[e1];
        float M1, M2; int I1;
        if (a1 <= b1) { M1 = a1; I1 = ai; M2 = fminf(a2, b1); }
        else          { M1 = b1; I1 = bi; M2 = fminf(b2, a1); }
        size_t p = (size_t)nb * N_ + (size_t)mb * 128 + t;
        pm1[p] = M1; pm2[p] = M2; pi1[p] = I1;
    }
}

// ---- k_merge: fold partials -> idx/counts/classification + sum(M1)+sum(z^2) -> loss ----
__global__ __launch_bounds__(256) void k_merge(const float* __restrict__ pm1,
                                               const float* __restrict__ pm2,
                                               const int* __restrict__ pi1,
                                               const float* __restrict__ S1,
                                               const double* __restrict__ zpart,
                                               int* __restrict__ idx,
                                               int* __restrict__ counts,
                                               int* __restrict__ c8,
                                               unsigned char* __restrict__ ncand,
                                               int* __restrict__ list_c,
                                               int* __restrict__ nflag_c,
                                               int* __restrict__ list_f,
                                               int* __restrict__ nflag_f,
                                               double* __restrict__ loss_acc) {
    __shared__ double msh[256];
    int n = blockIdx.x * 256 + threadIdx.x;     // grid = 256
    float a1[8], a2[8]; int ai[8];
    float M1 = 3.4e38f, M2 = 3.4e38f; int I1 = 0;
    #pragma unroll
    for (int nb = 0; nb < 8; ++nb) {
        size_t p = (size_t)nb * N_ + n;
        a1[nb] = pm1[p]; a2[nb] = pm2[p]; ai[nb] = pi1[p];
        if (a1[nb] < M1) { M2 = fminf(M1, a2[nb]); M1 = a1[nb]; I1 = ai[nb]; }
        else             { M2 = fminf(M2, a1[nb]); }
    }
    idx[n] = I1;
    atomicAdd(&counts[I1], 1);
    float thr = M1 + fmaf(S1[n], MARGIN_A, MARGIN_B);
    bool fl = M2 < thr;
    bool needfull = false;
    int cnt = 0;
    if (fl) {
        #pragma unroll
        for (int nb = 0; nb < 8; ++nb) {
            if (a2[nb] < thr) needfull = true;
            if (a1[nb] < thr) ++cnt;
        }
    }
    bool candrow = fl && !needfull;
    bool fullrow = fl && needfull;
    if (candrow) {
        ncand[n] = (unsigned char)cnt;
        int pos = 0;
        #pragma unroll
        for (int nb = 0; nb < 8; ++nb)
            if (a1[nb] < thr) c8[(size_t)n * 8 + (pos++)] = ai[nb];  // ascending code order
    }
    int lane = threadIdx.x & 63;
    unsigned long long mc = __ballot(candrow);
    if (mc) {
        int base = 0;
        if (lane == 0) base = atomicAdd(nflag_c, __popcll(mc));
        base = __shfl(base, 0, 64);
        if (candrow) list_c[base + __popcll(mc & ((1ull << lane) - 1ull))] = n;
    }
    unsigned long long mf = __ballot(fullrow);
    if (mf) {
        int base = 0;
        if (lane == 0) base = atomicAdd(nflag_f, __popcll(mf));
        base = __shfl(base, 0, 64);
        if (fullrow) list_f[base + __popcll(mf & ((1ull << lane) - 1ull))] = n;
    }
    // loss partial: sum of per-row min scores; block 0 also folds z^2 partials
    double m1loss = (double)M1;
    if (blockIdx.x == 0) {
        double zs = 0.0;
        #pragma unroll
        for (int j = 0; j < 8; ++j) zs += zpart[threadIdx.x + 256 * j];
        m1loss += zs;
    }
    msh[threadIdx.x] = m1loss;
    __syncthreads();
    for (int off = 128; off; off >>= 1) {
        if (threadIdx.x < off) msh[threadIdx.x] += msh[threadIdx.x + off];
        __syncthreads();
    }
    if (threadIdx.x == 0) atomicAdd(loss_acc, msh[0]);
}

// ---- k_fixup: blocks 0..1023 = full-K f64 rescan; 1024..1279 = cand2 rescore ----
__global__ __launch_bounds__(256) void k_fixup(const float* __restrict__ Z,
                                               const float* __restrict__ E,
                                               const float* __restrict__ Et,
                                               const double* __restrict__ e2d,
                                               const int* __restrict__ c8,
                                               const unsigned char* __restrict__ ncand,
                                               const int* __restrict__ list_c,
                                               const int* __restrict__ nflag_c,
                                               const int* __restrict__ list_f,
                                               const int* __restrict__ nflag_f,
                                               int* __restrict__ idx,
                                               int* __restrict__ counts) {
    __shared__ float  zs[8][257];
    __shared__ int    sn[8];
    __shared__ double rbv[8][4];
    __shared__ int    rbi[8][4];
    int t = threadIdx.x, w = t >> 6, l = t & 63;

    if (blockIdx.x >= 1024) {
        // ---- cand2: exact f64 rescore of <=8 known candidates, one wave per row ----
        int nf = *nflag_c;
        int gw = (blockIdx.x - 1024) * 4 + w;     // 1024 waves
        for (int ii = gw; ii < nf; ii += 1024) {
            int n = list_c[ii];
            int b = n >> 10, hw = n & (HW_ - 1);
            const float* zp = Z + (size_t)b * (D_ * HW_) + hw;
            double z0 = (double)zp[(size_t)(l      ) * HW_];
            double z1 = (double)zp[(size_t)(l +  64) * HW_];
            double z2 = (double)zp[(size_t)(l + 128) * HW_];
            double z3 = (double)zp[(size_t)(l + 192) * HW_];
            int nc = ncand[n];
            double bv = 1e300; int bi = 0;
            for (int j = 0; j < nc; ++j) {        // candidates ascend in code index
                int c = c8[(size_t)n * 8 + j];
                const float* er = E + (size_t)c * D_;
                double s = z0 * (double)er[l];
                s = fma(z1, (double)er[l +  64], s);
                s = fma(z2, (double)er[l + 128], s);
                s = fma(z3, (double)er[l + 192], s);
                #pragma unroll
                for (int off = 32; off; off >>= 1) s += __shfl_xor(s, off, 64);
                double sc = fma(-2.0, s, e2d[c]);  // z^2 cancels in ranking
                if (sc < bv || (sc == bv && c < bi)) { bv = sc; bi = c; }
            }
            if (l == 0) {
                int old = idx[n];
                if (bi != old) {
                    idx[n] = bi;
                    atomicSub(&counts[old], 1);
                    atomicAdd(&counts[bi], 1);
                }
            }
        }
        return;
    }

    // ---- rescan8: exact f64 full-K fallback, 8 rows/chunk, 8x d-unroll ----
    int nf = *nflag_f;
    double ed0 = e2d[4 * t + 0], ed1 = e2d[4 * t + 1];
    double ed2 = e2d[4 * t + 2], ed3 = e2d[4 * t + 3];

    for (int ch = blockIdx.x; ch * 8 < nf; ch += 1024) {
        __syncthreads();
        int i0 = ch * 8;
        int vc = min(8, nf - i0);
        if (t < 8) sn[t] = list_f[i0 + min(t, vc - 1)];
        __syncthreads();

        #pragma unroll
        for (int j = 0; j < 8; ++j) {
            int n = sn[j];
            zs[j][t] = Z[(size_t)(n >> 10) * (D_ * HW_) + (size_t)t * HW_ + (n & (HW_ - 1))];
        }
        __syncthreads();

        double s[8][4];
        #pragma unroll
        for (int r = 0; r < 8; ++r)
            s[r][0] = s[r][1] = s[r][2] = s[r][3] = 0.0;

        for (int d0 = 0; d0 < 256; d0 += 8) {
            float4 e4v[8];
            #pragma unroll
            for (int u = 0; u < 8; ++u)
                e4v[u] = *(const float4*)(Et + (size_t)(d0 + u) * K_ + 4 * t);
            #pragma unroll
            for (int u = 0; u < 8; ++u) {
                double ex = (double)e4v[u].x, ey = (double)e4v[u].y;
                double ez = (double)e4v[u].z, ew = (double)e4v[u].w;
                #pragma unroll
                for (int r = 0; r < 8; ++r) {
                    double zv = (double)zs[r][d0 + u];
                    s[r][0] = fma(zv, ex, s[r][0]);
                    s[r][1] = fma(zv, ey, s[r][1]);
                    s[r][2] = fma(zv, ez, s[r][2]);
                    s[r][3] = fma(zv, ew, s[r][3]);
                }
            }
        }

        #pragma unroll
        for (int r = 0; r < 8; ++r) {
            double bv = fma(-2.0, s[r][0], ed0); int bi = 4 * t;
            double c1 = fma(-2.0, s[r][1], ed1);
            double c2 = fma(-2.0, s[r][2], ed2);
            double c3 = fma(-2.0, s[r][3], ed3);
            if (c1 < bv) { bv = c1; bi = 4 * t + 1; }
            if (c2 < bv) { bv = c2; bi = 4 * t + 2; }
            if (c3 < bv) { bv = c3; bi = 4 * t + 3; }
            #pragma unroll
            for (int off = 1; off < 64; off <<= 1) {
                double ov = __shfl_xor(bv, off, 64);
                int    oi = __shfl_xor(bi, off, 64);
                if (ov < bv || (ov == bv && oi < bi)) { bv = ov; bi = oi; }
            }
            if (l == 0) { rbv[r][w] = bv; rbi[r][w] = bi; }
        }
        __syncthreads();

        if (t < vc) {
            double bv = rbv[t][0]; int bi = rbi[t][0];
            #pragma unroll
            for (int ww = 1; ww < 4; ++ww) {
                double ov = rbv[t][ww]; int oi = rbi[t][ww];
                if (ov < bv || (ov == bv && oi < bi)) { bv = ov; bi = oi; }
            }
            int n = sn[t];
            int old = idx[n];
            if (bi != old) {
                idx[n] = bi;
                atomicSub(&counts[old], 1);
                atomicAdd(&counts[bi], 1);
            }
        }
    }
}

// ---- k_gatherfinal: blocks 0..2047 = E-scatter to NCHW out; block 2048 = scalars ----
__global__ __launch_bounds__(256) void k_gatherfinal(const float* __restrict__ E,
                                                     const int* __restrict__ idx,
                                                     const int* __restrict__ counts,
                                                     const double* __restrict__ loss_acc,
                                                     float* __restrict__ out) {
    int t = threadIdx.x;
    if (blockIdx.x == 2048) {
        __shared__ double sh[256];
        double s = 0.0;
        for (int k = t; k < K_; k += 256) {
            double p = (double)counts[k] / (double)N_;
            s += p * log(p + 1e-10);
        }
        sh[t] = s; __syncthreads();
        for (int off = 128; off; off >>= 1) {
            if (t < off) sh[t] += sh[t + off];
            __syncthreads();
        }
        if (t == 0) {
            out[0]       = (float)((*loss_acc) / (double)ND_ * 1.25);
            out[1 + ND_] = (float)exp(-sh[0]);
        }
        return;
    }
    __shared__ float ecache[32][257];
    __shared__ int sidx[32];
    int n0 = blockIdx.x * 32;                 // 2048 blocks
    int b = n0 >> 10, hw0 = n0 & (HW_ - 1);
    if (t < 32) sidx[t] = idx[n0 + t];
    __syncthreads();
    #pragma unroll 8
    for (int j = 0; j < 32; ++j)
        ecache[j][t] = E[(size_t)sidx[j] * D_ + t];
    __syncthreads();
    int hw = t & 31, cq = t >> 5;
    float* ob = out + 1 + (size_t)b * (D_ * HW_) + hw0 + hw;
    #pragma unroll 8
    for (int jj = 0; jj < 32; ++jj) {
        int c = cq * 32 + jj;
        ob[(size_t)c * HW_] = ecache[hw][c];
    }
}

extern "C" void kernel_launch(void* const* d_in, const int* in_sizes, int n_in,
                              void* d_out, int out_size, void* d_ws, size_t ws_size,
                              hipStream_t stream) {
    (void)in_sizes; (void)n_in; (void)out_size; (void)ws_size;
    const float* Z = (const float*)d_in[0];
    const float* E = (const float*)d_in[1];
    float* out = (float*)d_out;

    char* ws = (char*)d_ws;
    unsigned short* Zh       = (unsigned short*)(ws);              // 32 MB
    unsigned short* Eh       = (unsigned short*)(ws + 33554432);   // 512 KB
    float*          Et       = (float*)(ws + 34078720);            // 1 MB
    float*          e2f      = (float*)(ws + 35127296);            // 4 KB
    double*         e2d      = (double*)(ws + 35131392);           // 8 KB
    float*          S1       = (float*)(ws + 35139584);            // 256 KB
    float*          pm1      = (float*)(ws + 35401728);            // 2 MB
    float*          pm2      = (float*)(ws + 37498880);            // 2 MB
    int*            pi1      = (int*)  (ws + 39596032);            // 2 MB
    int*            idx      = (int*)  (ws + 41693184);            // 256 KB
    int*            list_f   = (int*)  (ws + 41955328);            // 256 KB
    int*            list_c   = (int*)  (ws + 42217472);            // 256 KB
    int*            c8       = (int*)  (ws + 42479616);            // 2 MB
    unsigned char*  ncand    = (unsigned char*)(ws + 44576768);    // 64 KB
    int*            counts   = (int*)  (ws + 44642304);            // 4 KB
    int*            nflag_f  = (int*)  (ws + 44646400);            // 64 B
    int*            nflag_c  = (int*)  (ws + 44646464);            // 64 B
    double*         loss_acc = (double*)(ws + 44646528);           // 64 B
    double*         zpart    = (double*)(ws + 44646592);           // 16 KB

    k_startup    <<<dim3(3072), dim3(256), 0, stream>>>(Z, E, Eh, Et, e2f, e2d, Zh, S1,
                                                        zpart, counts, nflag_f, nflag_c, loss_acc);
    k_phase1     <<<dim3(4096), dim3(256), 0, stream>>>(Zh, Eh, e2f, pm1, pm2, pi1);
    k_merge      <<<dim3(256),  dim3(256), 0, stream>>>(pm1, pm2, pi1, S1, zpart, idx, counts,
                                                        c8, ncand, list_c, nflag_c, list_f, nflag_f, loss_acc);
    k_fixup      <<<dim3(1280), dim3(256), 0, stream>>>(Z, E, Et, e2d, c8, ncand,
                                                        list_c, nflag_c, list_f, nflag_f, idx, counts);
    k_gatherfinal<<<dim3(2049), dim3(256), 0, stream>>>(E, idx, counts, loss_acc, out);
}